// Round 4
// baseline (216.996 us; speedup 1.0000x reference)
//
#include <hip/hip_runtime.h>

// Problem constants (reference: L=4, B=32, T=2048, D=100)
constexpr int kL = 4;
constexpr int kB = 32;
constexpr int kT = 2048;
constexpr int kD = 100;
constexpr int kD4 = kD / 4;            // 25 float4 per t-row
constexpr int kCH = 16;                // t-chunks per (l,b) slab
constexpr int kTSUB = kT / kCH;        // 128 t-rows per chunk
constexpr int kLB = kL * kB;           // 128 (l,b) slabs
constexpr int kROWS = kLB * kD;        // 12800 (l,b,d) softmax rows
constexpr int kNBLK = kLB * kCH;       // 2048 blocks in pass 1

// R6 theory: reads capped by per-CU outstanding-line tracking (MSHR ~64 lines)
// x loaded latency. plain: 2.52 TB/s (L~835ns), nt: ~3.5 TB/s (L~600ns) -- both
// per-CU caps, explaining ILP-insensitivity (R3/R4 nulls). global_load_lds has
// no VGPR return -> not MSHR-tracked the same way; in-flight bounded by tile
// size. This round: LDS-direct staging (aux=2 keeps the NT no-allocate bit).

// Per-element KL contribution: S_p += exp(oh), S_q += exp(h), W += exp(oh)*(oh-h).
// No max-subtraction: N(0,1) logits, exp cannot overflow fp32 (absmax=0 in prior rounds).
#define KL_PAIR(hx, ox)                                                      \
  {                                                                          \
    const float ea = __expf(ox.x), eb = __expf(ox.y), ec = __expf(ox.z),     \
                ed = __expf(ox.w);                                           \
    sp.x += ea; sp.y += eb; sp.z += ec; sp.w += ed;                          \
    sq.x += __expf(hx.x); sq.y += __expf(hx.y);                              \
    sq.z += __expf(hx.z); sq.w += __expf(hx.w);                              \
    w.x += ea * (ox.x - hx.x); w.y += eb * (ox.y - hx.y);                    \
    w.z += ec * (ox.z - hx.z); w.w += ed * (ox.w - hx.w);                    \
  }

typedef float vfloat4 __attribute__((ext_vector_type(4)));
typedef const __attribute__((address_space(1))) void gvoid_t;
typedef __attribute__((address_space(3))) void lvoid_t;

__device__ __forceinline__ float4 ntload4(const float4* __restrict__ p) {
  const vfloat4 v = __builtin_nontemporal_load((const vfloat4*)p);
  return make_float4(v.x, v.y, v.z, v.w);
}

// ---------------- Path A pass 1: LDS-direct staged streaming ----------------
// Block (lb, chunk) covers 128 t-rows; 4 subtiles of 32 rows. Per subtile the
// 25600-B region [h 12800 | oh 12800] is staged by 25 global_load_lds x 1024 B:
// LDS dest = tile + k*1024 (wave-uniform; HW adds lane*16), global src per-lane
// with a h/oh select (only instr k=12 straddles the boundary). All 64 lanes
// stage; compute keeps the 50-lane (half,d4) fixed-d mapping.
__global__ __launch_bounds__(256) void kl_partial_na(
    const float4* __restrict__ h4, const float4* __restrict__ oh4,
    float* __restrict__ psp, float* __restrict__ psq, float* __restrict__ pw) {
  const int lb = blockIdx.x >> 4;
  const int chunk = blockIdx.x & 15;
  const int tid = threadIdx.x;
  const int ty = tid >> 6;             // wave 0..3
  const int lane = tid & 63;
  const int half = lane / kD4;         // 0,1 active; lanes 50..63 compute-idle
  const int d4 = lane - half * kD4;
  const bool active = (lane < 2 * kD4);

  __shared__ float4 tile[1600];        // [0,800)=h subtile, [800,1600)=oh subtile
  __shared__ float red[256][12];

  float4 sp = {0.f, 0.f, 0.f, 0.f};
  float4 sq = {0.f, 0.f, 0.f, 0.f};
  float4 w  = {0.f, 0.f, 0.f, 0.f};

  const size_t blockbyte = ((size_t)lb * kT + chunk * kTSUB) * 400;  // 400 B/row
  const char* __restrict__ hb0 = (const char*)h4 + blockbyte;
  const char* __restrict__ ob0 = (const char*)oh4 + blockbyte;
  char* const tl = (char*)&tile[0];

  for (int s = 0; s < 4; ++s) {
    const char* __restrict__ hb = hb0 + s * 12800;   // 32 rows x 400 B
    const char* __restrict__ ob = ob0 + s * 12800;
    // --- stage: wave ty issues k = ty, ty+4, ... (6-7 instr, back-to-back) ---
    for (int k = ty; k < 25; k += 4) {
      const int off = k * 1024 + lane * 16;          // byte in [0, 25600)
      const char* src = (off < 12800) ? (hb + off) : (ob + (off - 12800));
      __builtin_amdgcn_global_load_lds((gvoid_t*)(const void*)src,
                                       (lvoid_t*)(void*)(tl + k * 1024),
                                       16, 0, 2 /*aux: NT bit (gfx94x+ CPol)*/);
    }
    asm volatile("s_waitcnt vmcnt(0)" ::: "memory");
    __syncthreads();                    // tile complete for all waves
    // --- compute: thread (ty,half,d4) handles rows ty*2+half+8*k2, k2=0..3 ---
    if (active) {
#pragma unroll
      for (int k2 = 0; k2 < 4; ++k2) {
        const int r = ty * 2 + half + k2 * 8;        // [0,32)
        const float4 hv = tile[r * kD4 + d4];
        const float4 ov = tile[800 + r * kD4 + d4];
        KL_PAIR(hv, ov)
      }
    }
    __syncthreads();                    // before next stage overwrites tile
  }

  // Block reduce: 8 contributors per d (4 waves x 2 row-halves), then 3 stores/d.
  {
    float* r = red[tid];
    r[0] = sp.x; r[1] = sp.y; r[2]  = sp.z; r[3]  = sp.w;
    r[4] = sq.x; r[5] = sq.y; r[6]  = sq.z; r[7]  = sq.w;
    r[8] = w.x;  r[9] = w.y;  r[10] = w.z;  r[11] = w.w;
  }
  __syncthreads();
  if (tid < kD) {
    const int dd4 = tid >> 2, j = tid & 3;
    float asp = 0.f, asq = 0.f, aw = 0.f;
#pragma unroll
    for (int g = 0; g < 4; ++g) {
#pragma unroll
      for (int hh = 0; hh < 2; ++hh) {
        const float* sdat = red[g * 64 + hh * kD4 + dd4];
        asp += sdat[j]; asq += sdat[4 + j]; aw += sdat[8 + j];
      }
    }
    const int base = blockIdx.x * kD + tid;   // (lb*16+chunk)*100 + d
    psp[base] = asp;
    psq[base] = asq;
    pw[base]  = aw;
  }
}

// Pass 2: one block per lb. Sums 16 chunk-partials per d, applies the
// nonlinearity, weights by softmax(lw)[l]*softmax(cw)[d]/B, writes lbsum[lb].
__global__ __launch_bounds__(256) void kl_reduce_na(
    const float* __restrict__ psp, const float* __restrict__ psq,
    const float* __restrict__ pw, const float* __restrict__ lwin,
    const float* __restrict__ cwin, float* __restrict__ lbsum) {
  const int lb = blockIdx.x;           // 0..127
  const int tid = threadIdx.x;
  __shared__ float lwS;                // softmax(layer_weights)[l] for this block
  __shared__ float cw[kD];
  __shared__ float sred[256];

  if (tid == 0) {
    float m = lwin[0];
    for (int i = 1; i < kL; ++i) m = fmaxf(m, lwin[i]);
    float e[kL], s = 0.f;
    for (int i = 0; i < kL; ++i) { e[i] = __expf(lwin[i] - m); s += e[i]; }
    lwS = e[lb / kB] / s;
  }
  if (tid == 64) {
    float m = cwin[0];
    for (int i = 1; i < kD; ++i) m = fmaxf(m, cwin[i]);
    float s = 0.f;
    for (int i = 0; i < kD; ++i) { const float e = __expf(cwin[i] - m); cw[i] = e; s += e; }
    const float inv = 1.0f / s;
    for (int i = 0; i < kD; ++i) cw[i] *= inv;
  }
  __syncthreads();

  float acc = 0.f;
  if (tid < kD) {
    float asp = 0.f, asq = 0.f, aw = 0.f;
#pragma unroll
    for (int c = 0; c < kCH; ++c) {
      const int idx = (lb * kCH + c) * kD + tid;
      asp += psp[idx]; asq += psq[idx]; aw += pw[idx];
    }
    const float val = aw / asp - __logf(asp) + __logf(asq);
    acc = lwS * cw[tid] * val * (1.0f / (float)kB);
  }
  sred[tid] = acc;
  __syncthreads();
  for (int s = 128; s > 0; s >>= 1) {
    if (tid < s) sred[tid] += sred[tid + s];
    __syncthreads();
  }
  if (tid == 0) lbsum[lb] = sred[0];
}

// Pass 3: one wave sums the 128 per-lb scalars and writes the loss.
__global__ void kl_final(const float* __restrict__ lbsum, float* __restrict__ out) {
  const int tid = threadIdx.x;         // 64 threads
  float v = lbsum[tid] + lbsum[tid + 64];
  for (int off = 32; off > 0; off >>= 1) v += __shfl_down(v, off);
  if (tid == 0) out[0] = v;
}

// ---------------- Path B: fallback if ws too small (old nt+atomic scheme) -----
__device__ __forceinline__ void stream_slab(const float4* __restrict__ hp,
                                            const float4* __restrict__ op,
                                            float4& sp, float4& sq, float4& w) {
#pragma unroll
  for (int i = 0; i < 4; ++i) {
    const float4 h0 = ntload4(hp + 0);
    const float4 h1 = ntload4(hp + 200);
    const float4 h2 = ntload4(hp + 400);
    const float4 h3 = ntload4(hp + 600);
    const float4 o0 = ntload4(op + 0);
    const float4 o1 = ntload4(op + 200);
    const float4 o2 = ntload4(op + 400);
    const float4 o3 = ntload4(op + 600);
    hp += 800; op += 800;
    __builtin_amdgcn_sched_barrier(0);
    KL_PAIR(h0, o0)
    KL_PAIR(h1, o1)
    KL_PAIR(h2, o2)
    KL_PAIR(h3, o3)
  }
}

__global__ __launch_bounds__(256) void kl_partial_at(
    const float4* __restrict__ h4, const float4* __restrict__ oh4,
    float* __restrict__ wsp, float* __restrict__ wsq, float* __restrict__ ww) {
  const int lb = blockIdx.x >> 4;
  const int chunk = blockIdx.x & 15;
  const int tid = threadIdx.x;
  const int ty = tid >> 6;
  const int lane = tid & 63;
  const int half = lane / kD4;
  const int d4 = lane - half * kD4;
  const bool active = (lane < 2 * kD4);

  float4 sp = {0.f, 0.f, 0.f, 0.f};
  float4 sq = {0.f, 0.f, 0.f, 0.f};
  float4 w  = {0.f, 0.f, 0.f, 0.f};
  if (active) {
    const int row0 = chunk * kTSUB + ty * 2 + half;
    const size_t b4 = ((size_t)lb * kT + row0) * kD4 + d4;
    stream_slab(h4 + b4, oh4 + b4, sp, sq, w);
  }

  __shared__ float red[256][12];
  {
    float* r = red[tid];
    r[0] = sp.x; r[1] = sp.y; r[2]  = sp.z; r[3]  = sp.w;
    r[4] = sq.x; r[5] = sq.y; r[6]  = sq.z; r[7]  = sq.w;
    r[8] = w.x;  r[9] = w.y;  r[10] = w.z;  r[11] = w.w;
  }
  __syncthreads();
  if (tid < kD) {
    const int dd4 = tid >> 2, j = tid & 3;
    float asp = 0.f, asq = 0.f, aw = 0.f;
#pragma unroll
    for (int g = 0; g < 4; ++g) {
#pragma unroll
      for (int hh = 0; hh < 2; ++hh) {
        const float* s = red[g * 64 + hh * kD4 + dd4];
        asp += s[j]; asq += s[4 + j]; aw += s[8 + j];
      }
    }
    const int idx = lb * kD + tid;
    atomicAdd(&wsp[idx], asp);
    atomicAdd(&wsq[idx], asq);
    atomicAdd(&ww[idx],  aw);
  }
}

__global__ __launch_bounds__(256) void kl_reduce_at(
    const float* __restrict__ wsp, const float* __restrict__ wsq,
    const float* __restrict__ ww, const float* __restrict__ lwin,
    const float* __restrict__ cwin, float* __restrict__ acc) {
  __shared__ float lw[kL];
  __shared__ float cw[kD];
  __shared__ float sred[256];
  const int tid = threadIdx.x;

  if (tid == 0) {
    float m = lwin[0];
    for (int i = 1; i < kL; ++i) m = fmaxf(m, lwin[i]);
    float e[kL], s = 0.f;
    for (int i = 0; i < kL; ++i) { e[i] = __expf(lwin[i] - m); s += e[i]; }
    const float inv = 1.0f / s;
    for (int i = 0; i < kL; ++i) lw[i] = e[i] * inv;
  }
  if (tid == 64) {
    float m = cwin[0];
    for (int i = 1; i < kD; ++i) m = fmaxf(m, cwin[i]);
    float s = 0.f;
    for (int i = 0; i < kD; ++i) { const float e = __expf(cwin[i] - m); cw[i] = e; s += e; }
    const float inv = 1.0f / s;
    for (int i = 0; i < kD; ++i) cw[i] *= inv;
  }
  __syncthreads();

  const int r = blockIdx.x * 256 + tid;
  const int l = r / (kB * kD);
  const int d = r % kD;
  const float spv = wsp[r], sqv = wsq[r], wv = ww[r];
  const float val = wv / spv - __logf(spv) + __logf(sqv);
  sred[tid] = lw[l] * cw[d] * val;
  __syncthreads();
  for (int s = 128; s > 0; s >>= 1) {
    if (tid < s) sred[tid] += sred[tid + s];
    __syncthreads();
  }
  if (tid == 0) atomicAdd(acc, sred[0]);
}

__global__ void kl_write(const float* __restrict__ acc, float* __restrict__ out) {
  out[0] = acc[0] / (float)kB;
}

extern "C" void kernel_launch(void* const* d_in, const int* in_sizes, int n_in,
                              void* d_out, int out_size, void* d_ws, size_t ws_size,
                              hipStream_t stream) {
  const float* h    = (const float*)d_in[0];  // [L,B,T,D] fp32
  const float* oh   = (const float*)d_in[1];  // [L,B,T,D] fp32
  const float* lwin = (const float*)d_in[2];  // [L] fp32
  const float* cwin = (const float*)d_in[3];  // [D] fp32

  const size_t needA = ((size_t)3 * kNBLK * kD + kLB) * sizeof(float);  // ~2.46 MB
  if (ws_size >= needA) {
    // Path A: 3 dispatches, no memset, no atomics. Every ws slot written
    // unconditionally, so 0xAA poison is harmless.
    float* psp   = (float*)d_ws;                 // [2048*100]
    float* psq   = psp + (size_t)kNBLK * kD;     // [2048*100]
    float* pw    = psq + (size_t)kNBLK * kD;     // [2048*100]
    float* lbsum = pw  + (size_t)kNBLK * kD;     // [128]
    kl_partial_na<<<kNBLK, 256, 0, stream>>>(
        (const float4*)h, (const float4*)oh, psp, psq, pw);
    kl_reduce_na<<<kLB, 256, 0, stream>>>(psp, psq, pw, lwin, cwin, lbsum);
    kl_final<<<1, 64, 0, stream>>>(lbsum, (float*)d_out);
  } else {
    // Path B: previous nt+atomic scheme (fits in 153.6 KB of ws).
    float* wsp = (float*)d_ws;
    float* wsq = wsp + kROWS;
    float* ww  = wsq + kROWS;
    float* acc = ww + kROWS;
    (void)hipMemsetAsync(d_ws, 0, ((size_t)3 * kROWS + 1) * sizeof(float), stream);
    kl_partial_at<<<kNBLK, 256, 0, stream>>>(
        (const float4*)h, (const float4*)oh, wsp, wsq, ww);
    kl_reduce_at<<<kROWS / 256, 256, 0, stream>>>(wsp, wsq, ww, lwin, cwin, acc);
    kl_write<<<1, 1, 0, stream>>>(acc, (float*)d_out);
  }
}